// Round 2
// 434.283 us; speedup vs baseline: 1.0043x; 1.0043x over previous
//
#include <hip/hip_runtime.h>

// newIF forward: T=8 IF-neuron scan + compensated per-neuron threshold.
// x layout: [T, B, C, H, W] flattened as (T*B, C, H, W) -> timestep stride is
// n4 float4's. One thread handles 4 contiguous neurons across all 8 steps.
//
// R2: nontemporal loads/stores via native clang vector type (HIP float4 is a
// class -> rejected by the builtin). Pure streaming kernel (537 MB, zero
// reuse, input 268 MB > 256 MB L3): bypass L2/LLC allocation with the `nt`
// cache flag to reach fill-kernel-like BW (~6.5 TB/s observed on the
// re-poison fills) instead of ~5.1 TB/s with allocating accesses.
constexpr int T_STEPS = 8;

typedef float f32x4 __attribute__((ext_vector_type(4)));

__global__ __launch_bounds__(256) void newif_kernel(
    const f32x4* __restrict__ x, const float* __restrict__ thresh,
    f32x4* __restrict__ out, long n4)
{
    long i = (long)blockIdx.x * blockDim.x + threadIdx.x;
    if (i >= n4) return;

    const float thre = thresh[0];
    const float half_thre = 0.5f * thre;

    const f32x4* __restrict__ xi = x + i;
    f32x4* __restrict__ oi = out + i;

    // Load all 8 timesteps up front (independent loads -> compiler overlaps,
    // emits vmcnt(7)..vmcnt(0) incremental waits).
    f32x4 xt[T_STEPS];
#pragma unroll
    for (int t = 0; t < T_STEPS; ++t)
        xt[t] = __builtin_nontemporal_load(xi + (long)t * n4);

    float mem[4] = {half_thre, half_thre, half_thre, half_thre};
    float cnt[4] = {0.f, 0.f, 0.f, 0.f};
    unsigned spikes = 0u;  // bit (t*4+c): did component c spike at step t

#pragma unroll
    for (int t = 0; t < T_STEPS; ++t) {
#pragma unroll
        for (int c = 0; c < 4; ++c) {
            mem[c] += xt[t][c];
            // zif(mem - thre): (mem - thre >= 0) == (mem >= thre) in fp32
            if (mem[c] >= thre) {
                mem[c] -= thre;           // same op as reference's mem - spike*thre
                cnt[c] += 1.0f;
                spikes |= 1u << (t * 4 + c);
            }
        }
    }

    float nt[4];
#pragma unroll
    for (int c = 0; c < 4; ++c) {
        float compen_mem = mem[c] - half_thre;
        float compen_value = fminf(compen_mem + cnt[c] * thre, (float)T_STEPS * thre);
        bool cond = (compen_value > 0.0f) && (cnt[c] > 0.0f);
        nt[c] = cond ? (compen_value / cnt[c]) : 0.0f;  // IEEE fp32 div
    }

#pragma unroll
    for (int t = 0; t < T_STEPS; ++t) {
        f32x4 o;
        o[0] = ((spikes >> (t * 4 + 0)) & 1u) ? nt[0] : 0.0f;
        o[1] = ((spikes >> (t * 4 + 1)) & 1u) ? nt[1] : 0.0f;
        o[2] = ((spikes >> (t * 4 + 2)) & 1u) ? nt[2] : 0.0f;
        o[3] = ((spikes >> (t * 4 + 3)) & 1u) ? nt[3] : 0.0f;
        __builtin_nontemporal_store(o, oi + (long)t * n4);
    }
}

extern "C" void kernel_launch(void* const* d_in, const int* in_sizes, int n_in,
                              void* d_out, int out_size, void* d_ws, size_t ws_size,
                              hipStream_t stream) {
    const float* x      = (const float*)d_in[0];
    const float* thresh = (const float*)d_in[1];
    float* out          = (float*)d_out;

    long n_total = (long)in_sizes[0];        // T*B*C*H*W = 67,108,864
    long n4      = n_total / T_STEPS / 4;    // float4's per timestep = 2,097,152

    const int block = 256;
    int grid = (int)((n4 + block - 1) / block);  // 8192 blocks
    newif_kernel<<<grid, block, 0, stream>>>(
        (const f32x4*)x, thresh, (f32x4*)out, n4);
}